// Round 1
// baseline (2959.340 us; speedup 1.0000x reference)
//
#include <hip/hip_runtime.h>
#include <stdint.h>

// SelfAttention: N=4, L=2048, E=1024, H=16, D=64
// Round 1: correct fp32 baseline. 4 kernels: mask-pack, QKV projection
// (K written transposed), flash-style attention (16 q-rows/wave, readlane
// broadcasts), tiled output GEMM.

static constexpr int N_ = 4, L_ = 2048, E_ = 1024, H_ = 16, D_ = 64;
static constexpr float SCALE_ = 0.03125f; // 1/sqrt(E) = 1/32

__device__ __forceinline__ float rdlane(float v, int lane) {
    return __int_as_float(__builtin_amdgcn_readlane(__float_as_int(v), lane));
}

// ---------------- mask pack: 1 bit per (n,q,k) -----------------------------
// grid: 65536 blocks x 256 thr; wave w handles one 64-key chunk.
__global__ __launch_bounds__(256) void pack_mask_k(
    const int* __restrict__ mask, unsigned long long* __restrict__ mpk) {
    int wid  = blockIdx.x * 4 + (threadIdx.x >> 6); // 0..262143
    int lane = threadIdx.x & 63;
    int c = wid & 31;
    int q = (wid >> 5) & (L_ - 1);
    int n = wid >> 16;
    int v = mask[(n * L_ + q) * L_ + c * 64 + lane];
    unsigned long long b = __ballot(v != 0);
    if (lane == 0) mpk[(n * L_ + q) * 32 + c] = b;
}

// ---------------- projection: out = X @ W^T per head -----------------------
// block: one (n,h,l-chunk of 64) -> 64(l) x 64(e) tile.
// which (blockIdx.y): 0 = Q -> qp[nh][l][e], 1 = K -> kT[nh][e][l], 2 = V -> vp[nh][l][e]
__global__ __launch_bounds__(256) void proj_k(
    const float* __restrict__ qin, const float* __restrict__ kin,
    const float* __restrict__ vin,
    const float* __restrict__ Wq, const float* __restrict__ Wk,
    const float* __restrict__ Wv,
    float* __restrict__ qp, float* __restrict__ kT, float* __restrict__ vp) {
    int which = blockIdx.y;
    const float* in = (which == 0) ? qin : (which == 1) ? kin : vin;
    const float* W  = (which == 0) ? Wq  : (which == 1) ? Wk  : Wv;
    int b  = blockIdx.x;          // n(2b) h(4b) lc(5b)
    int lc = b & 31;
    int h  = (b >> 5) & 15;
    int n  = b >> 9;
    int l0 = lc * 64;
    int nh = n * H_ + h;

    __shared__ float X[64 * 65];
    __shared__ float Wl[64 * 65];
    int t = threadIdx.x;
    #pragma unroll
    for (int i = 0; i < 16; ++i) {
        int idx = t + i * 256;            // 0..4095
        int row = idx >> 6, col = idx & 63;
        X[row * 65 + col]  = in[(n * L_ + l0 + row) * E_ + h * D_ + col];
        Wl[row * 65 + col] = W[row * 64 + col];   // W[e][d]
    }
    __syncthreads();

    int e = t & 63;
    int rbase = (t >> 6) * 16;
    float acc[16];
    #pragma unroll
    for (int i = 0; i < 16; ++i) acc[i] = 0.f;
    for (int d = 0; d < 64; ++d) {
        float w = Wl[e * 65 + d];          // lane-varying row, banks (e+d)%32: free
        #pragma unroll
        for (int i = 0; i < 16; ++i)
            acc[i] += X[(rbase + i) * 65 + d] * w;   // uniform broadcast
    }
    __syncthreads();
    // park tile[l][e] back in X, then write in coalesced orientation
    #pragma unroll
    for (int i = 0; i < 16; ++i) X[(rbase + i) * 65 + e] = acc[i];
    __syncthreads();

    if (which == 1) {
        #pragma unroll
        for (int i = 0; i < 16; ++i) {
            int idx = t + i * 256;
            int erow = idx >> 6, lcol = idx & 63;
            kT[(nh * D_ + erow) * L_ + l0 + lcol] = X[lcol * 65 + erow];
        }
    } else {
        float* out = (which == 0) ? qp : vp;
        #pragma unroll
        for (int i = 0; i < 16; ++i) {
            int idx = t + i * 256;
            int row = idx >> 6, col = idx & 63;
            out[(nh * L_ + l0 + row) * D_ + col] = X[row * 65 + col];
        }
    }
}

// ---------------- attention: one wave = 16 q-rows of one (n,h) -------------
__global__ __launch_bounds__(256) void attn_k(
    const float* __restrict__ qp, const float* __restrict__ kT,
    const float* __restrict__ vp, const unsigned long long* __restrict__ mpk,
    float* __restrict__ ao) {
    constexpr int RPW = 16;
    int wid  = blockIdx.x * 4 + (threadIdx.x >> 6); // 0..8191
    int lane = threadIdx.x & 63;
    int qg = wid & (L_ / RPW - 1);  // 0..127
    int nh = wid >> 7;              // 0..63
    int q0 = qg * RPW;
    int n  = nh >> 4, h = nh & 15;

    const float* qbase = qp + (nh * L_ + q0) * D_;
    const float* kb    = kT + nh * D_ * L_;
    const float* vb    = vp + nh * L_ * D_;
    const unsigned long long* mb = mpk + (n * L_ + q0) * 32;

    float qreg[RPW], m[RPW], lsum[RPW], o[RPW];
    #pragma unroll
    for (int r = 0; r < RPW; ++r) {
        qreg[r] = qbase[r * D_ + lane];   // lane = d
        m[r] = -1e30f; lsum[r] = 0.f; o[r] = 0.f;
    }

    for (int c = 0; c < 32; ++c) {
        // ---- scores: lanes = keys (coalesced reads of kT) ----
        float s[RPW];
        #pragma unroll
        for (int r = 0; r < RPW; ++r) s[r] = 0.f;
        const float* kc = kb + c * 64 + lane;
        #pragma unroll 4
        for (int d = 0; d < 64; ++d) {
            float kd = kc[d * L_];
            #pragma unroll
            for (int r = 0; r < RPW; ++r)
                s[r] += rdlane(qreg[r], d) * kd;
        }
        // ---- mask + online softmax per row ----
        float p[RPW];
        #pragma unroll
        for (int r = 0; r < RPW; ++r) {
            unsigned long long mbr = mb[r * 32 + c];
            bool act = (mbr >> lane) & 1ULL;
            float tv = act ? s[r] * SCALE_ : -1e30f;
            float cm = tv;
            #pragma unroll
            for (int off = 32; off; off >>= 1)
                cm = fmaxf(cm, __shfl_xor(cm, off));
            float mn = fmaxf(m[r], cm);
            float al = __expf(m[r] - mn);
            p[r] = act ? __expf(tv - mn) : 0.f;
            lsum[r] = lsum[r] * al + p[r];   // lane-partial sum
            o[r] *= al;
            m[r] = mn;
        }
        // ---- PV: lanes = d (coalesced reads of vp) ----
        const float* vc = vb + c * 64 * D_ + lane;
        #pragma unroll 4
        for (int k = 0; k < 64; ++k) {
            float vk = vc[k * D_];
            #pragma unroll
            for (int r = 0; r < RPW; ++r)
                o[r] += rdlane(p[r], k) * vk;
        }
    }
    #pragma unroll
    for (int r = 0; r < RPW; ++r) {
        float tot = lsum[r];
        #pragma unroll
        for (int off = 32; off; off >>= 1) tot += __shfl_xor(tot, off);
        ao[(n * L_ + q0 + r) * E_ + h * D_ + lane] = o[r] / tot;
    }
}

// ---------------- output GEMM: Y = ao @ Wo^T + bo --------------------------
// tile 64x64, BK=16, thread = 4x4 outputs.
__global__ __launch_bounds__(256) void out_gemm_k(
    const float* __restrict__ A, const float* __restrict__ Wo,
    const float* __restrict__ bo, float* __restrict__ Y) {
    __shared__ float As[16 * 68];
    __shared__ float Bs[16 * 68];
    int t = threadIdx.x;
    int row0 = blockIdx.x * 64, col0 = blockIdx.y * 64;
    int tk = t & 15, tr = t >> 4;   // staging: k fast, row slow
    int tx = t & 15, ty = t >> 4;   // compute: tx->m4, ty->n4
    float acc[4][4];
    #pragma unroll
    for (int i = 0; i < 4; ++i)
        #pragma unroll
        for (int j = 0; j < 4; ++j) acc[i][j] = 0.f;

    for (int kt = 0; kt < 64; ++kt) {
        int k0 = kt * 16;
        #pragma unroll
        for (int pp = 0; pp < 4; ++pp) {
            int mr = tr + pp * 16;
            As[tk * 68 + mr] = A[(row0 + mr) * E_ + k0 + tk];
            Bs[tk * 68 + mr] = Wo[(col0 + mr) * E_ + k0 + tk];
        }
        __syncthreads();
        #pragma unroll
        for (int k = 0; k < 16; ++k) {
            float4 a4 = *(const float4*)&As[k * 68 + tx * 4];
            float4 b4 = *(const float4*)&Bs[k * 68 + ty * 4];
            float av[4] = {a4.x, a4.y, a4.z, a4.w};
            float bv[4] = {b4.x, b4.y, b4.z, b4.w};
            #pragma unroll
            for (int i = 0; i < 4; ++i)
                #pragma unroll
                for (int j = 0; j < 4; ++j) acc[i][j] += av[i] * bv[j];
        }
        __syncthreads();
    }
    float4 bb = *(const float4*)&bo[col0 + ty * 4];
    float bvv[4] = {bb.x, bb.y, bb.z, bb.w};
    #pragma unroll
    for (int i = 0; i < 4; ++i) {
        float4 v;
        v.x = acc[i][0] + bvv[0];
        v.y = acc[i][1] + bvv[1];
        v.z = acc[i][2] + bvv[2];
        v.w = acc[i][3] + bvv[3];
        *(float4*)&Y[(row0 + tx * 4 + i) * E_ + col0 + ty * 4] = v;
    }
}

extern "C" void kernel_launch(void* const* d_in, const int* in_sizes, int n_in,
                              void* d_out, int out_size, void* d_ws, size_t ws_size,
                              hipStream_t stream) {
    const float* values  = (const float*)d_in[0];
    const float* keys    = (const float*)d_in[1];
    const float* queries = (const float*)d_in[2];
    const int*   mask    = (const int*)  d_in[3];
    const float* Wq      = (const float*)d_in[4];
    const float* Wk      = (const float*)d_in[5];
    const float* Wv      = (const float*)d_in[6];
    const float* Wo      = (const float*)d_in[7];
    const float* bo      = (const float*)d_in[8];
    float* Y = (float*)d_out;

    // workspace layout (floats)
    float* ws = (float*)d_ws;
    const size_t SZ = (size_t)N_ * H_ * L_ * D_;   // 8388608
    float* qp = ws;
    float* kT = ws + SZ;
    float* vp = ws + 2 * SZ;
    float* ao = ws + 3 * SZ;
    unsigned long long* mpk = (unsigned long long*)(ws + 4 * SZ);

    pack_mask_k<<<N_ * L_ * 32 / 4, 256, 0, stream>>>(mask, mpk);
    proj_k<<<dim3(N_ * H_ * (L_ / 64), 3), 256, 0, stream>>>(
        queries, keys, values, Wq, Wk, Wv, qp, kT, vp);
    attn_k<<<N_ * H_ * (L_ / 16) / 4, 256, 0, stream>>>(qp, kT, vp, mpk, ao);
    out_gemm_k<<<dim3(N_ * L_ / 64, E_ / 64), 256, 0, stream>>>(ao, Wo, bo, Y);
}

// Round 2
// 756.854 us; speedup vs baseline: 3.9101x; 3.9101x over previous
//
#include <hip/hip_runtime.h>
#include <stdint.h>

// SelfAttention N=4, L=2048, E=1024, H=16, D=64.
// Round 2: bf16 MFMA attention (swapped QK^T, lane-local softmax) + MFMA out-GEMM.

static constexpr int N_ = 4, L_ = 2048, E_ = 1024, H_ = 16, D_ = 64;
static constexpr float SCALE_ = 0.03125f; // 1/sqrt(E)

typedef __bf16 bf16_t;
typedef __attribute__((ext_vector_type(8))) __bf16 bf16x8;
typedef __attribute__((ext_vector_type(4))) float f32x4;

__device__ __forceinline__ f32x4 mfma16(bf16x8 a, bf16x8 b, f32x4 c) {
    return __builtin_amdgcn_mfma_f32_16x16x32_bf16(a, b, c, 0, 0, 0);
}

// ---------------- mask pack: 1 bit per (n,q,k) -----------------------------
__global__ __launch_bounds__(256) void pack_mask_k(
    const int* __restrict__ mask, unsigned long long* __restrict__ mpk) {
    int wid  = blockIdx.x * 4 + (threadIdx.x >> 6);
    int lane = threadIdx.x & 63;
    int c = wid & 31;
    int q = (wid >> 5) & (L_ - 1);
    int n = wid >> 16;
    int v = mask[((size_t)n * L_ + q) * L_ + c * 64 + lane];
    unsigned long long b = __ballot(v != 0);
    if (lane == 0) mpk[((size_t)n * L_ + q) * 32 + c] = b;
}

// ---------------- Wo fp32 -> bf16 ------------------------------------------
__global__ __launch_bounds__(256) void cvt_wo_k(
    const float* __restrict__ Wo, bf16_t* __restrict__ WoB) {
    int i = blockIdx.x * 256 + threadIdx.x;
    WoB[i] = (bf16_t)Wo[i];
}

// ---------------- projection: out = X @ W^T per head, bf16 outputs ---------
// which: 0 = Q -> qB[nh][l][d], 1 = K -> kB[nh][l][d], 2 = V -> vT[nh][d][l]
__global__ __launch_bounds__(256) void proj_k(
    const float* __restrict__ qin, const float* __restrict__ kin,
    const float* __restrict__ vin,
    const float* __restrict__ Wq, const float* __restrict__ Wk,
    const float* __restrict__ Wv,
    bf16_t* __restrict__ qB, bf16_t* __restrict__ kB, bf16_t* __restrict__ vT) {
    int which = blockIdx.y;
    const float* in = (which == 0) ? qin : (which == 1) ? kin : vin;
    const float* W  = (which == 0) ? Wq  : (which == 1) ? Wk  : Wv;
    int b  = blockIdx.x;
    int lc = b & 31;
    int h  = (b >> 5) & 15;
    int n  = b >> 9;
    int l0 = lc * 64;
    int nh = n * H_ + h;

    __shared__ float X[64 * 65];
    __shared__ float Wl[64 * 65];
    int t = threadIdx.x;
    #pragma unroll
    for (int i = 0; i < 16; ++i) {
        int idx = t + i * 256;
        int row = idx >> 6, col = idx & 63;
        X[row * 65 + col]  = in[((size_t)n * L_ + l0 + row) * E_ + h * D_ + col];
        Wl[row * 65 + col] = W[row * 64 + col];
    }
    __syncthreads();

    int e = t & 63;
    int rbase = (t >> 6) * 16;
    float acc[16];
    #pragma unroll
    for (int i = 0; i < 16; ++i) acc[i] = 0.f;
    for (int d = 0; d < 64; ++d) {
        float w = Wl[e * 65 + d];
        #pragma unroll
        for (int i = 0; i < 16; ++i)
            acc[i] += X[(rbase + i) * 65 + d] * w;
    }
    __syncthreads();
    #pragma unroll
    for (int i = 0; i < 16; ++i) X[(rbase + i) * 65 + e] = acc[i];
    __syncthreads();

    if (which == 2) {
        #pragma unroll
        for (int i = 0; i < 16; ++i) {
            int idx = t + i * 256;
            int erow = idx >> 6, lcol = idx & 63;
            vT[((size_t)nh * D_ + erow) * L_ + l0 + lcol] = (bf16_t)X[lcol * 65 + erow];
        }
    } else {
        bf16_t* out = (which == 0) ? qB : kB;
        #pragma unroll
        for (int i = 0; i < 16; ++i) {
            int idx = t + i * 256;
            int row = idx >> 6, col = idx & 63;
            out[((size_t)nh * L_ + l0 + row) * D_ + col] = (bf16_t)X[row * 65 + col];
        }
    }
}

// ---------------- MFMA flash attention -------------------------------------
// Wave = 16 q-rows of one (n,h). Block = 4 waves = 64 q-rows.
// Swapped QK^T: st[s] holds S^T[k=s*16+4g+r][q=lane&15] -> softmax lane-local in q.
__global__ __launch_bounds__(256) void attn_mfma_k(
    const bf16_t* __restrict__ qB, const bf16_t* __restrict__ kB,
    const bf16_t* __restrict__ vT, const unsigned long long* __restrict__ mpk,
    bf16_t* __restrict__ aoB) {
    int b = blockIdx.x;
    int xcd = b & 7, idx = b >> 3;       // XCD-pinned (n,h): one XCD owns 8 nh
    int nh = xcd * 8 + (idx >> 5);
    int qt = idx & 31;
    int n = nh >> 4, h = nh & 15;
    int wv = threadIdx.x >> 6;
    int lane = threadIdx.x & 63;
    int g = lane >> 4, qi = lane & 15;
    int q0 = qt * 64 + wv * 16;

    const bf16_t* qb = qB + ((size_t)nh * L_ + q0) * D_;
    const bf16_t* kb = kB + (size_t)nh * L_ * D_;
    const bf16_t* vb = vT + (size_t)nh * D_ * L_;
    const unsigned long long* mb = mpk + ((size_t)n * L_ + q0 + qi) * 32;

    // Q fragments, held for the whole loop (B-frag: n=qi, k=d)
    bf16x8 qf0 = *(const bf16x8*)(qb + qi * D_ + 8 * g);
    bf16x8 qf1 = *(const bf16x8*)(qb + qi * D_ + 32 + 8 * g);

    f32x4 o[4];
    #pragma unroll
    for (int dt = 0; dt < 4; ++dt) o[dt] = (f32x4){0.f, 0.f, 0.f, 0.f};
    float m = -1e30f, lsum = 0.f;

    for (int t = 0; t < 32; ++t) {
        const bf16_t* kt = kb + (size_t)t * 64 * D_;
        // S^T: 4 subtiles of 16 keys, contraction over d in 2 chunks of 32
        f32x4 st[4];
        #pragma unroll
        for (int s = 0; s < 4; ++s) {
            f32x4 c = (f32x4){0.f, 0.f, 0.f, 0.f};
            c = mfma16(*(const bf16x8*)(kt + (s * 16 + qi) * D_ + 8 * g), qf0, c);
            c = mfma16(*(const bf16x8*)(kt + (s * 16 + qi) * D_ + 32 + 8 * g), qf1, c);
            st[s] = c;
        }
        // mask + online softmax (per lane: q=qi, k=s*16+4g+r)
        unsigned long long w = mb[t];
        float p[4][4];
        float tm = -1e30f;
        #pragma unroll
        for (int s = 0; s < 4; ++s)
            #pragma unroll
            for (int r = 0; r < 4; ++r) {
                int kl = s * 16 + 4 * g + r;
                bool act = (w >> kl) & 1ULL;
                float sv = act ? st[s][r] * SCALE_ : -1e30f;
                p[s][r] = sv;
                tm = fmaxf(tm, sv);
            }
        tm = fmaxf(tm, __shfl_xor(tm, 16));
        tm = fmaxf(tm, __shfl_xor(tm, 32));
        float mn = fmaxf(m, tm);
        float al = __expf(m - mn);
        float ps = 0.f;
        #pragma unroll
        for (int s = 0; s < 4; ++s)
            #pragma unroll
            for (int r = 0; r < 4; ++r) {
                float pv = (p[s][r] > -1e29f) ? __expf(p[s][r] - mn) : 0.f;
                p[s][r] = pv;
                ps += pv;
            }
        lsum = lsum * al + ps;
        m = mn;
        // rescale O (O rows live as q=4g+r -> fetch al from lane 4g+r)
        float alo[4];
        #pragma unroll
        for (int r = 0; r < 4; ++r) alo[r] = __shfl(al, 4 * g + r);
        #pragma unroll
        for (int dt = 0; dt < 4; ++dt)
            #pragma unroll
            for (int r = 0; r < 4; ++r) o[dt][r] *= alo[r];
        // PV: build P A-fragments (k-map consistent with V B-load), 2 chunks of 32 keys
        #pragma unroll
        for (int kc = 0; kc < 2; ++kc) {
            bf16x8 pa;
            #pragma unroll
            for (int i = 0; i < 8; ++i) {
                int r = i & 3;
                int srcl = (2 * (g & 1) + (i >> 2)) * 16 + qi;
                float v0 = __shfl(p[kc * 2][r], srcl);
                float v1 = __shfl(p[kc * 2 + 1][r], srcl);
                pa[i] = (bf16_t)((g >> 1) ? v1 : v0);
            }
            #pragma unroll
            for (int dt = 0; dt < 4; ++dt) {
                bf16x8 vf = *(const bf16x8*)(vb + (size_t)(dt * 16 + qi) * L_ +
                                             t * 64 + kc * 32 + 8 * g);
                o[dt] = mfma16(pa, vf, o[dt]);
            }
        }
    }
    // final normalize + store (O: q=4g+r, d=dt*16+qi)
    lsum += __shfl_xor(lsum, 16);
    lsum += __shfl_xor(lsum, 32);
    float ls[4];
    #pragma unroll
    for (int r = 0; r < 4; ++r) ls[r] = __shfl(lsum, 4 * g + r);
    #pragma unroll
    for (int r = 0; r < 4; ++r) {
        int q = q0 + 4 * g + r;
        #pragma unroll
        for (int dt = 0; dt < 4; ++dt)
            aoB[((size_t)n * L_ + q) * E_ + h * 64 + dt * 16 + qi] =
                (bf16_t)(o[dt][r] / ls[r]);
    }
}

// ---------------- output GEMM: Y = ao @ Wo^T + bo (MFMA) -------------------
__global__ __launch_bounds__(256) void out_gemm_mfma_k(
    const bf16_t* __restrict__ A, const bf16_t* __restrict__ WoB,
    const float* __restrict__ bo, float* __restrict__ Y) {
    int rt = blockIdx.x, ct = blockIdx.y;
    int wv = threadIdx.x >> 6, lane = threadIdx.x & 63;
    int g = lane >> 4, qi = lane & 15;
    int row0 = rt * 64 + wv * 16, col0 = ct * 64;
    f32x4 acc[4];
    #pragma unroll
    for (int et = 0; et < 4; ++et) acc[et] = (f32x4){0.f, 0.f, 0.f, 0.f};
    const bf16_t* ar = A + (size_t)(row0 + qi) * E_;
    for (int k0 = 0; k0 < E_; k0 += 32) {
        bf16x8 af = *(const bf16x8*)(ar + k0 + 8 * g);
        #pragma unroll
        for (int et = 0; et < 4; ++et) {
            bf16x8 bfr = *(const bf16x8*)(WoB + (size_t)(col0 + et * 16 + qi) * E_ +
                                          k0 + 8 * g);
            acc[et] = mfma16(af, bfr, acc[et]);
        }
    }
    #pragma unroll
    for (int et = 0; et < 4; ++et) {
        float bias = bo[col0 + et * 16 + qi];
        #pragma unroll
        for (int r = 0; r < 4; ++r)
            Y[(size_t)(row0 + 4 * g + r) * E_ + col0 + et * 16 + qi] =
                acc[et][r] + bias;
    }
}

extern "C" void kernel_launch(void* const* d_in, const int* in_sizes, int n_in,
                              void* d_out, int out_size, void* d_ws, size_t ws_size,
                              hipStream_t stream) {
    const float* values  = (const float*)d_in[0];
    const float* keys    = (const float*)d_in[1];
    const float* queries = (const float*)d_in[2];
    const int*   mask    = (const int*)  d_in[3];
    const float* Wq      = (const float*)d_in[4];
    const float* Wk      = (const float*)d_in[5];
    const float* Wv      = (const float*)d_in[6];
    const float* Wo      = (const float*)d_in[7];
    const float* bo      = (const float*)d_in[8];
    float* Y = (float*)d_out;

    const size_t SZ = (size_t)N_ * H_ * L_ * D_;  // 8388608 elements
    bf16_t* qB  = (bf16_t*)d_ws;
    bf16_t* kB  = qB + SZ;
    bf16_t* vT  = kB + SZ;
    bf16_t* aoB = vT + SZ;
    unsigned long long* mpk = (unsigned long long*)(aoB + SZ);
    bf16_t* WoB = (bf16_t*)(mpk + (size_t)N_ * L_ * 32);

    pack_mask_k<<<N_ * L_ * 32 / 4, 256, 0, stream>>>(mask, mpk);
    cvt_wo_k<<<E_ * E_ / 256, 256, 0, stream>>>(Wo, WoB);
    proj_k<<<dim3(N_ * H_ * (L_ / 64), 3), 256, 0, stream>>>(
        queries, keys, values, Wq, Wk, Wv, qB, kB, vT);
    attn_mfma_k<<<N_ * H_ * (L_ / 64), 256, 0, stream>>>(qB, kB, vT, mpk, aoB);
    out_gemm_mfma_k<<<dim3(N_ * L_ / 64, E_ / 64), 256, 0, stream>>>(aoB, WoB, bo, Y);
}

// Round 3
// 541.613 us; speedup vs baseline: 5.4639x; 1.3974x over previous
//
#include <hip/hip_runtime.h>
#include <stdint.h>

// SelfAttention N=4, L=2048, E=1024, H=16, D=64.
// Round 3: 32x32 MFMA attention, swapped QK^T, lane-local softmax (exp2
// domain), defer-max rescale, P-frag build via pair-pack + 4 half-swaps.

static constexpr int N_ = 4, L_ = 2048, E_ = 1024, H_ = 16, D_ = 64;

typedef __bf16 bf16_t;
typedef __attribute__((ext_vector_type(8))) __bf16 bf16x8;
typedef __attribute__((ext_vector_type(4))) float f32x4;
typedef __attribute__((ext_vector_type(16))) float f32x16;
typedef __attribute__((ext_vector_type(4))) unsigned int uint4v;

__device__ __forceinline__ f32x4 mfma16(bf16x8 a, bf16x8 b, f32x4 c) {
    return __builtin_amdgcn_mfma_f32_16x16x32_bf16(a, b, c, 0, 0, 0);
}
__device__ __forceinline__ f32x16 mfma32(bf16x8 a, bf16x8 b, f32x16 c) {
    return __builtin_amdgcn_mfma_f32_32x32x16_bf16(a, b, c, 0, 0, 0);
}
__device__ __forceinline__ unsigned int pk2(float a, float b) {
    union { bf16_t h[2]; unsigned int u; } z;
    z.h[0] = (bf16_t)a; z.h[1] = (bf16_t)b;
    return z.u;
}

// ---------------- mask pack: 1 bit per (n,q,k) -----------------------------
__global__ __launch_bounds__(256) void pack_mask_k(
    const int* __restrict__ mask, unsigned long long* __restrict__ mpk) {
    int wid  = blockIdx.x * 4 + (threadIdx.x >> 6);
    int lane = threadIdx.x & 63;
    int c = wid & 31;
    int q = (wid >> 5) & (L_ - 1);
    int n = wid >> 16;
    int v = mask[((size_t)n * L_ + q) * L_ + c * 64 + lane];
    unsigned long long b = __ballot(v != 0);
    if (lane == 0) mpk[((size_t)n * L_ + q) * 32 + c] = b;
}

// ---------------- Wo fp32 -> bf16 ------------------------------------------
__global__ __launch_bounds__(256) void cvt_wo_k(
    const float* __restrict__ Wo, bf16_t* __restrict__ WoB) {
    int i = blockIdx.x * 256 + threadIdx.x;
    WoB[i] = (bf16_t)Wo[i];
}

// ---------------- projection: out = X @ W^T per head, bf16 outputs ---------
__global__ __launch_bounds__(256) void proj_k(
    const float* __restrict__ qin, const float* __restrict__ kin,
    const float* __restrict__ vin,
    const float* __restrict__ Wq, const float* __restrict__ Wk,
    const float* __restrict__ Wv,
    bf16_t* __restrict__ qB, bf16_t* __restrict__ kB, bf16_t* __restrict__ vT) {
    int which = blockIdx.y;
    const float* in = (which == 0) ? qin : (which == 1) ? kin : vin;
    const float* W  = (which == 0) ? Wq  : (which == 1) ? Wk  : Wv;
    int b  = blockIdx.x;
    int lc = b & 31;
    int h  = (b >> 5) & 15;
    int n  = b >> 9;
    int l0 = lc * 64;
    int nh = n * H_ + h;

    __shared__ float X[64 * 65];
    __shared__ float Wl[64 * 65];
    int t = threadIdx.x;
    #pragma unroll
    for (int i = 0; i < 16; ++i) {
        int idx = t + i * 256;
        int row = idx >> 6, col = idx & 63;
        X[row * 65 + col]  = in[((size_t)n * L_ + l0 + row) * E_ + h * D_ + col];
        Wl[row * 65 + col] = W[row * 64 + col];
    }
    __syncthreads();

    int e = t & 63;
    int rbase = (t >> 6) * 16;
    float acc[16];
    #pragma unroll
    for (int i = 0; i < 16; ++i) acc[i] = 0.f;
    for (int d = 0; d < 64; ++d) {
        float w = Wl[e * 65 + d];
        #pragma unroll
        for (int i = 0; i < 16; ++i)
            acc[i] += X[(rbase + i) * 65 + d] * w;
    }
    __syncthreads();
    #pragma unroll
    for (int i = 0; i < 16; ++i) X[(rbase + i) * 65 + e] = acc[i];
    __syncthreads();

    if (which == 2) {
        #pragma unroll
        for (int i = 0; i < 16; ++i) {
            int idx = t + i * 256;
            int erow = idx >> 6, lcol = idx & 63;
            vT[((size_t)nh * D_ + erow) * L_ + l0 + lcol] = (bf16_t)X[lcol * 65 + erow];
        }
    } else {
        bf16_t* out = (which == 0) ? qB : kB;
        #pragma unroll
        for (int i = 0; i < 16; ++i) {
            int idx = t + i * 256;
            int row = idx >> 6, col = idx & 63;
            out[((size_t)nh * L_ + l0 + row) * D_ + col] = (bf16_t)X[row * 65 + col];
        }
    }
}

// ---------------- 32x32 MFMA flash attention -------------------------------
// Wave = 32 q-rows of one (n,h); block = 4 waves = 128 q-rows.
// Swapped QK^T: S^T C-layout col=q=lane&31, row k=(r&3)+8*(r>>2)+4*hi.
__global__ __launch_bounds__(256) void attn_mfma32_k(
    const bf16_t* __restrict__ qB, const bf16_t* __restrict__ kB,
    const bf16_t* __restrict__ vT, const unsigned int* __restrict__ mpk32,
    bf16_t* __restrict__ aoB) {
    int b = blockIdx.x;
    int xcd = b & 7, idx = b >> 3;       // pin each nh-group to one XCD
    int nh = xcd * 8 + (idx >> 4);
    int qt = idx & 15;
    int n = nh >> 4, h = nh & 15;
    int w = threadIdx.x >> 6, lane = threadIdx.x & 63;
    int lo5 = lane & 31, hi = lane >> 5;
    int q0 = qt * 128 + w * 32;

    const bf16_t* qb = qB + ((size_t)nh * L_ + q0) * D_;
    const bf16_t* kb = kB + (size_t)nh * L_ * D_;
    const bf16_t* vb = vT + (size_t)nh * D_ * L_;
    const unsigned int* mrow = mpk32 + ((size_t)n * L_ + q0 + lo5) * 64;

    // Q B-frags (col=q=lo5, k=d), held all kernel: 4 chunks of d
    bf16x8 qf[4];
    #pragma unroll
    for (int c = 0; c < 4; ++c)
        qf[c] = *(const bf16x8*)(qb + lo5 * D_ + c * 16 + hi * 8);

    f32x16 o0, o1;
    #pragma unroll
    for (int r = 0; r < 16; ++r) { o0[r] = 0.f; o1[r] = 0.f; }
    float m = 0.f, negm = 0.f, lsum = 0.f;
    const float csc = 0.03125f * 1.44269504f;   // scale * log2(e)

    for (int t = 0; t < 64; ++t) {
        const bf16_t* kt = kb + (size_t)t * 32 * D_;
        f32x16 st;
        #pragma unroll
        for (int r = 0; r < 16; ++r) st[r] = 0.f;
        #pragma unroll
        for (int c = 0; c < 4; ++c) {
            bf16x8 kf = *(const bf16x8*)(kt + lo5 * D_ + c * 16 + hi * 8);
            st = mfma32(kf, qf[c], st);
        }
        // mask + scale + running-max bias (exp2 domain), all lane-local
        unsigned int mw = mrow[t];
        unsigned int mwh = hi ? (mw >> 4) : mw;
        float sv[16];
        float tmx = -1e30f;
        #pragma unroll
        for (int r = 0; r < 16; ++r) {
            int kr = (r & 3) + 8 * (r >> 2);
            float bias = ((mwh >> kr) & 1u) ? negm : -10000.f;
            sv[r] = fmaf(st[r], csc, bias);
            tmx = fmaxf(tmx, sv[r]);
        }
        tmx = fmaxf(tmx, __shfl_xor(tmx, 32));
        float gr = 0.f;
        if (__any(tmx > 8.f)) {              // defer-max: rare
            gr = fmaxf(tmx, 0.f);
            m += gr; negm = -m;
            float al = exp2f(-gr);
            lsum *= al;
            #pragma unroll
            for (int r = 0; r < 16; ++r) {
                int qr = (r & 3) + 8 * (r >> 2) + 4 * hi;
                float alr = __shfl(al, qr);
                o0[r] *= alr; o1[r] *= alr;
            }
        }
        float p[16], ps = 0.f;
        #pragma unroll
        for (int r = 0; r < 16; ++r) {
            p[r] = exp2f(sv[r] - gr);
            ps += p[r];
        }
        lsum += ps;
        // P -> A-frag: pack bf16 pairs, exchange halves (k map: (r&3)+8*(r>>2)+4hi)
        unsigned int w0 = pk2(p[0],  p[1]),  w1 = pk2(p[2],  p[3]);
        unsigned int w2 = pk2(p[4],  p[5]),  w3 = pk2(p[6],  p[7]);
        unsigned int w4 = pk2(p[8],  p[9]),  w5 = pk2(p[10], p[11]);
        unsigned int w6 = pk2(p[12], p[13]), w7 = pk2(p[14], p[15]);
        unsigned int r1 = __shfl_xor(hi ? w0 : w2, 32);
        unsigned int r2 = __shfl_xor(hi ? w1 : w3, 32);
        unsigned int r3 = __shfl_xor(hi ? w4 : w6, 32);
        unsigned int r4 = __shfl_xor(hi ? w5 : w7, 32);
        uint4v fa0, fa1;
        fa0.x = hi ? r1 : w0;  fa0.y = hi ? r2 : w1;
        fa0.z = hi ? w2 : r1;  fa0.w = hi ? w3 : r2;
        fa1.x = hi ? r3 : w4;  fa1.y = hi ? r4 : w5;
        fa1.z = hi ? w6 : r3;  fa1.w = hi ? w7 : r4;
        bf16x8 pa0 = __builtin_bit_cast(bf16x8, fa0);
        bf16x8 pa1 = __builtin_bit_cast(bf16x8, fa1);
        // PV: O[q][d] += P V, V B-frags contiguous from vT[d][l]
        const bf16_t* vt0 = vb + (size_t)lo5 * L_ + t * 32 + hi * 8;
        const bf16_t* vt1 = vt0 + (size_t)32 * L_;
        o0 = mfma32(pa0, *(const bf16x8*)(vt0), o0);
        o0 = mfma32(pa1, *(const bf16x8*)(vt0 + 16), o0);
        o1 = mfma32(pa0, *(const bf16x8*)(vt1), o1);
        o1 = mfma32(pa1, *(const bf16x8*)(vt1 + 16), o1);
    }
    // epilogue: combine halves of lsum, normalize, store
    float lt = lsum + __shfl_xor(lsum, 32);
    #pragma unroll
    for (int r = 0; r < 16; ++r) {
        int qr = (r & 3) + 8 * (r >> 2) + 4 * hi;
        float inv = __builtin_amdgcn_rcpf(__shfl(lt, qr));
        bf16_t* orow = aoB + ((size_t)n * L_ + q0 + qr) * E_ + h * 64;
        orow[lo5]      = (bf16_t)(o0[r] * inv);
        orow[32 + lo5] = (bf16_t)(o1[r] * inv);
    }
}

// ---------------- output GEMM: Y = ao @ Wo^T + bo (MFMA) -------------------
__global__ __launch_bounds__(256) void out_gemm_mfma_k(
    const bf16_t* __restrict__ A, const bf16_t* __restrict__ WoB,
    const float* __restrict__ bo, float* __restrict__ Y) {
    int rt = blockIdx.x, ct = blockIdx.y;
    int wv = threadIdx.x >> 6, lane = threadIdx.x & 63;
    int g = lane >> 4, qi = lane & 15;
    int row0 = rt * 64 + wv * 16, col0 = ct * 64;
    f32x4 acc[4];
    #pragma unroll
    for (int et = 0; et < 4; ++et) acc[et] = (f32x4){0.f, 0.f, 0.f, 0.f};
    const bf16_t* ar = A + (size_t)(row0 + qi) * E_;
    for (int k0 = 0; k0 < E_; k0 += 32) {
        bf16x8 af = *(const bf16x8*)(ar + k0 + 8 * g);
        #pragma unroll
        for (int et = 0; et < 4; ++et) {
            bf16x8 bfr = *(const bf16x8*)(WoB + (size_t)(col0 + et * 16 + qi) * E_ +
                                          k0 + 8 * g);
            acc[et] = mfma16(af, bfr, acc[et]);
        }
    }
    #pragma unroll
    for (int et = 0; et < 4; ++et) {
        float bias = bo[col0 + et * 16 + qi];
        #pragma unroll
        for (int r = 0; r < 4; ++r)
            Y[(size_t)(row0 + 4 * g + r) * E_ + col0 + et * 16 + qi] =
                acc[et][r] + bias;
    }
}

extern "C" void kernel_launch(void* const* d_in, const int* in_sizes, int n_in,
                              void* d_out, int out_size, void* d_ws, size_t ws_size,
                              hipStream_t stream) {
    const float* values  = (const float*)d_in[0];
    const float* keys    = (const float*)d_in[1];
    const float* queries = (const float*)d_in[2];
    const int*   mask    = (const int*)  d_in[3];
    const float* Wq      = (const float*)d_in[4];
    const float* Wk      = (const float*)d_in[5];
    const float* Wv      = (const float*)d_in[6];
    const float* Wo      = (const float*)d_in[7];
    const float* bo      = (const float*)d_in[8];
    float* Y = (float*)d_out;

    const size_t SZ = (size_t)N_ * H_ * L_ * D_;  // 8388608 elements
    bf16_t* qB  = (bf16_t*)d_ws;
    bf16_t* kB  = qB + SZ;
    bf16_t* vT  = kB + SZ;
    bf16_t* aoB = vT + SZ;
    unsigned long long* mpk = (unsigned long long*)(aoB + SZ);
    bf16_t* WoB = (bf16_t*)(mpk + (size_t)N_ * L_ * 32);

    pack_mask_k<<<N_ * L_ * 32 / 4, 256, 0, stream>>>(mask, mpk);
    cvt_wo_k<<<E_ * E_ / 256, 256, 0, stream>>>(Wo, WoB);
    proj_k<<<dim3(N_ * H_ * (L_ / 64), 3), 256, 0, stream>>>(
        queries, keys, values, Wq, Wk, Wv, qB, kB, vT);
    attn_mfma32_k<<<N_ * H_ * (L_ / 128), 256, 0, stream>>>(
        qB, kB, vT, (const unsigned int*)mpk, aoB);
    out_gemm_mfma_k<<<dim3(N_ * L_ / 64, E_ / 64), 256, 0, stream>>>(aoB, WoB, bo, Y);
}